// Round 2
// baseline (800.219 us; speedup 1.0000x reference)
//
#include <hip/hip_runtime.h>
#include <math.h>

// ---------------- GEMM: C[N,M] = A[N,K] * B[K,M], row-major ----------------
__global__ __launch_bounds__(256) void gemm_kernel(const float* __restrict__ A,
                                                   const float* __restrict__ B,
                                                   float* __restrict__ C,
                                                   int n, int k, int m) {
    __shared__ float As[16][68];
    __shared__ float Bs[16][68];
    const int row0 = blockIdx.x * 64;
    const int col0 = blockIdx.y * 64;
    const int tid = threadIdx.x;
    const int tr = tid >> 4;
    const int tc = tid & 15;
    float acc[4][4] = {};
    for (int k0 = 0; k0 < k; k0 += 16) {
        {
            const int kk = tid & 15;
            const int mbase = tid >> 4;
#pragma unroll
            for (int i = 0; i < 4; ++i) {
                const int mm = mbase + i * 16;
                const int row = row0 + mm;
                As[kk][mm] = (row < n) ? A[(size_t)row * k + k0 + kk] : 0.f;
            }
        }
        {
            const int nn = tid & 63;
            const int kbase = tid >> 6;
#pragma unroll
            for (int i = 0; i < 4; ++i) {
                const int kk = kbase + i * 4;
                Bs[kk][nn] = B[(size_t)(k0 + kk) * m + col0 + nn];
            }
        }
        __syncthreads();
#pragma unroll
        for (int kk = 0; kk < 16; ++kk) {
            float a[4], b[4];
#pragma unroll
            for (int i = 0; i < 4; ++i) a[i] = As[kk][tr * 4 + i];
#pragma unroll
            for (int j = 0; j < 4; ++j) b[j] = Bs[kk][tc * 4 + j];
#pragma unroll
            for (int i = 0; i < 4; ++i)
#pragma unroll
                for (int j = 0; j < 4; ++j) acc[i][j] += a[i] * b[j];
        }
        __syncthreads();
    }
#pragma unroll
    for (int i = 0; i < 4; ++i) {
        const int row = row0 + tr * 4 + i;
        if (row < n) {
#pragma unroll
            for (int j = 0; j < 4; ++j)
                C[(size_t)row * m + col0 + tc * 4 + j] = acc[i][j];
        }
    }
}

// ------------- per-node attention coefficients a_src, a_dst ---------------
template <int H, int C>
__global__ void att_kernel(const float* __restrict__ h,
                           const float* __restrict__ att_s,
                           const float* __restrict__ att_d,
                           float* __restrict__ as_, float* __restrict__ ad_,
                           int n) {
    const int idx = blockIdx.x * blockDim.x + threadIdx.x;
    if (idx >= n * H) return;
    const int node = idx / H;
    const int hh = idx % H;
    const float* hp = h + (size_t)node * H * C + hh * C;
    float s0 = 0.f, s1 = 0.f;
#pragma unroll
    for (int c = 0; c < C; ++c) {
        const float v = hp[c];
        s0 += v * att_s[hh * C + c];
        s1 += v * att_d[hh * C + c];
    }
    as_[idx] = s0;
    ad_[idx] = s1;
}

// ----------------------------- CSR build ----------------------------------
__global__ void deg_kernel(const int* __restrict__ dst, int* __restrict__ deg,
                           int e) {
    const int i = blockIdx.x * blockDim.x + threadIdx.x;
    if (i < e) atomicAdd(&deg[dst[i]], 1);
}

__global__ __launch_bounds__(1024) void scan1_kernel(const int* __restrict__ deg,
                                                     int* __restrict__ offs,
                                                     int* __restrict__ sums,
                                                     int n) {
    __shared__ int s[1024];
    const int t = threadIdx.x;
    const int i = blockIdx.x * 1024 + t;
    const int v = (i < n) ? deg[i] : 0;
    s[t] = v;
    __syncthreads();
    for (int d = 1; d < 1024; d <<= 1) {
        const int x = (t >= d) ? s[t - d] : 0;
        __syncthreads();
        s[t] += x;
        __syncthreads();
    }
    if (i < n) offs[i] = s[t] - v;
    if (t == 1023) sums[blockIdx.x] = s[1023];
}

__global__ __launch_bounds__(128) void scan2_kernel(int* sums, int nb) {
    __shared__ int s[128];
    const int t = threadIdx.x;
    const int v = (t < nb) ? sums[t] : 0;
    s[t] = v;
    __syncthreads();
    for (int d = 1; d < 128; d <<= 1) {
        const int x = (t >= d) ? s[t - d] : 0;
        __syncthreads();
        s[t] += x;
        __syncthreads();
    }
    if (t < nb) sums[t] = s[t] - v;
}

__global__ __launch_bounds__(1024) void scan3_kernel(int* __restrict__ offs,
                                                     const int* __restrict__ sums,
                                                     int* __restrict__ cursor,
                                                     int n) {
    const int i = blockIdx.x * 1024 + threadIdx.x;
    if (i < n) {
        const int o = offs[i] + sums[blockIdx.x];
        offs[i] = o;
        cursor[i] = o;
    }
}

__global__ void fill_kernel(const int* __restrict__ src,
                            const int* __restrict__ dst, int* cursor,
                            int* __restrict__ csr, int e) {
    const int i = blockIdx.x * blockDim.x + threadIdx.x;
    if (i < e) {
        const int p = atomicAdd(&cursor[dst[i]], 1);
        csr[p] = src[i];
    }
}

// -------- softmax denominator: linv[dst,h] = 1/(sum_e exp(lrelu(e)) + eps) -
// No max-shift: |e| <= ~12 for these inputs, exp() safely in f32 range, and
// alpha = exp(e)/sum exp(e) is shift-invariant (eps contribution <=1e-11 rel).
template <int H>
__global__ __launch_bounds__(64) void denom_kernel(
    const float* __restrict__ a_src, const float* __restrict__ a_dst,
    const int* __restrict__ csr, const int* __restrict__ offs,
    const int* __restrict__ deg, float* __restrict__ linv, int n) {
    const int dst = blockIdx.x;
    const int lane = threadIdx.x;
    const int start = offs[dst];
    const int d = deg[dst];
    float adv[H], L[H];
#pragma unroll
    for (int h = 0; h < H; ++h) {
        adv[h] = a_dst[dst * H + h];
        L[h] = 0.f;
    }
    for (int j = lane; j <= d; j += 64) {  // j==d is the self loop
        const int src = (j < d) ? csr[start + j] : dst;
#pragma unroll
        for (int h = 0; h < H; ++h) {
            float e = a_src[src * H + h] + adv[h];
            e = fmaxf(e, 0.2f * e);  // LeakyReLU(0.2)
            L[h] += __expf(e);
        }
    }
#pragma unroll
    for (int off = 32; off; off >>= 1)
#pragma unroll
        for (int h = 0; h < H; ++h) L[h] += __shfl_xor(L[h], off);
    if (lane < H) linv[dst * H + lane] = 1.f / (L[lane] + 1e-16f);
}

// --------- gather-aggregate with precomputed denominator ------------------
// One wave per dst node. Lane owns R consecutive channels (R*64 == H*C).
// Alpha chain computed once per lane for head (lane & (H-1)), broadcast via
// shuffle to the lanes whose channels live in that head.
template <int H, int C, bool DO_ELU>
__global__ __launch_bounds__(64) void agg_kernel(
    const float* __restrict__ h, const float* __restrict__ a_src,
    const float* __restrict__ a_dst, const float* __restrict__ linv,
    const int* __restrict__ csr, const int* __restrict__ offs,
    const int* __restrict__ deg, const float* __restrict__ bias,
    float* __restrict__ out, int n) {
    constexpr int HC = H * C;
    constexpr int R = HC / 64;  // 2 (layer1) or 1 (layer2)
    const int dst = blockIdx.x;
    const int lane = threadIdx.x;
    const int start = offs[dst];
    const int d = deg[dst];
    const int myh = lane & (H - 1);   // head whose alpha this lane computes
    const int ch0 = lane * R;         // first owned channel
    const int hh = ch0 / C;           // head of owned channels (R<=C, same head)
    const float advm = a_dst[dst * H + myh];
    const float li = linv[dst * H + myh];
    float acc[R];
#pragma unroll
    for (int r = 0; r < R; ++r) acc[r] = 0.f;

    for (int j = 0; j <= d; ++j) {  // j==d is the self loop
        const int src = (j < d) ? csr[start + j] : dst;
        float e = a_src[src * H + myh] + advm;
        e = fmaxf(e, 0.2f * e);
        const float al = __expf(e) * li;            // alpha for head myh
        const float au = (H > 1) ? __shfl(al, hh) : al;
        const float* hp = h + (size_t)src * HC + ch0;
        if (R == 2) {
            const float2 hv = *(const float2*)hp;
            acc[0] += au * hv.x;
            acc[1] += au * hv.y;
        } else {
            acc[0] += au * hp[0];
        }
    }
#pragma unroll
    for (int r = 0; r < R; ++r) {
        float res = acc[r] + bias[ch0 + r];
        if (DO_ELU) res = (res > 0.f) ? res : (__expf(res) - 1.f);
        acc[r] = res;
    }
    float* op = out + (size_t)dst * HC + ch0;
    if (R == 2) {
        *(float2*)op = make_float2(acc[0], acc[1]);
    } else {
        op[0] = acc[0];
    }
}

// --------------------------------------------------------------------------
extern "C" void kernel_launch(void* const* d_in, const int* in_sizes, int n_in,
                              void* d_out, int out_size, void* d_ws,
                              size_t ws_size, hipStream_t stream) {
    const float* x = (const float*)d_in[0];
    const int* ei = (const int*)d_in[1];
    const float* W1 = (const float*)d_in[2];
    const float* att_s1 = (const float*)d_in[3];
    const float* att_d1 = (const float*)d_in[4];
    const float* b1 = (const float*)d_in[5];
    const float* W2 = (const float*)d_in[6];
    const float* att_s2 = (const float*)d_in[7];
    const float* att_d2 = (const float*)d_in[8];
    const float* b2 = (const float*)d_in[9];

    const int N = in_sizes[0] / 256;  // 100000
    const int E = in_sizes[1] / 2;    // 1600000
    const int* srcp = ei;
    const int* dstp = ei + E;

    float* h1 = (float*)d_ws;             // N*128
    float* h1p = h1 + (size_t)N * 128;    // N*128
    float* as1 = h1p + (size_t)N * 128;   // N*4
    float* ad1 = as1 + (size_t)N * 4;     // N*4
    float* as2 = ad1 + (size_t)N * 4;     // N
    float* ad2 = as2 + N;                 // N
    float* linv1 = ad2 + N;               // N*4
    float* linv2 = linv1 + (size_t)N * 4; // N
    int* deg = (int*)(linv2 + N);         // N
    int* offs = deg + N;                  // N
    int* cursor = offs + N;               // N
    int* sums = cursor + N;               // 128
    int* csr = sums + 128;                // E
    float* h2 = h1;  // h1 dead after layer-1 aggregation

    const int nb = (N + 1023) / 1024;

    // ---- CSR build ----
    hipMemsetAsync(deg, 0, (size_t)N * 4, stream);
    deg_kernel<<<(E + 255) / 256, 256, 0, stream>>>(dstp, deg, E);
    scan1_kernel<<<nb, 1024, 0, stream>>>(deg, offs, sums, N);
    scan2_kernel<<<1, 128, 0, stream>>>(sums, nb);
    scan3_kernel<<<nb, 1024, 0, stream>>>(offs, sums, cursor, N);
    fill_kernel<<<(E + 255) / 256, 256, 0, stream>>>(srcp, dstp, cursor, csr, E);

    // ---- layer 1 ----
    {
        dim3 grid((N + 63) / 64, 128 / 64);
        gemm_kernel<<<grid, 256, 0, stream>>>(x, W1, h1, N, 256, 128);
    }
    att_kernel<4, 32><<<(N * 4 + 255) / 256, 256, 0, stream>>>(h1, att_s1,
                                                               att_d1, as1,
                                                               ad1, N);
    denom_kernel<4><<<N, 64, 0, stream>>>(as1, ad1, csr, offs, deg, linv1, N);
    agg_kernel<4, 32, true><<<N, 64, 0, stream>>>(h1, as1, ad1, linv1, csr,
                                                  offs, deg, b1, h1p, N);

    // ---- layer 2 ----
    {
        dim3 grid((N + 63) / 64, 64 / 64);
        gemm_kernel<<<grid, 256, 0, stream>>>(h1p, W2, h2, N, 128, 64);
    }
    att_kernel<1, 64><<<(N + 255) / 256, 256, 0, stream>>>(h2, att_s2, att_d2,
                                                           as2, ad2, N);
    denom_kernel<1><<<N, 64, 0, stream>>>(as2, ad2, csr, offs, deg, linv2, N);
    agg_kernel<1, 64, false><<<N, 64, 0, stream>>>(h2, as2, ad2, linv2, csr,
                                                   offs, deg, b2, (float*)d_out,
                                                   N);
}

// Round 4
// 712.063 us; speedup vs baseline: 1.1238x; 1.1238x over previous
//
#include <hip/hip_runtime.h>
#include <math.h>

// ---------------- GEMM: C[N,M] = A[N,K] * B[K,M], row-major ----------------
__global__ __launch_bounds__(256) void gemm_kernel(const float* __restrict__ A,
                                                   const float* __restrict__ B,
                                                   float* __restrict__ C,
                                                   int n, int k, int m) {
    __shared__ float As[16][68];
    __shared__ float Bs[16][68];
    const int row0 = blockIdx.x * 64;
    const int col0 = blockIdx.y * 64;
    const int tid = threadIdx.x;
    const int tr = tid >> 4;
    const int tc = tid & 15;
    float acc[4][4] = {};
    for (int k0 = 0; k0 < k; k0 += 16) {
        {
            const int kk = tid & 15;
            const int mbase = tid >> 4;
#pragma unroll
            for (int i = 0; i < 4; ++i) {
                const int mm = mbase + i * 16;
                const int row = row0 + mm;
                As[kk][mm] = (row < n) ? A[(size_t)row * k + k0 + kk] : 0.f;
            }
        }
        {
            const int nn = tid & 63;
            const int kbase = tid >> 6;
#pragma unroll
            for (int i = 0; i < 4; ++i) {
                const int kk = kbase + i * 4;
                Bs[kk][nn] = B[(size_t)(k0 + kk) * m + col0 + nn];
            }
        }
        __syncthreads();
#pragma unroll
        for (int kk = 0; kk < 16; ++kk) {
            float a[4], b[4];
#pragma unroll
            for (int i = 0; i < 4; ++i) a[i] = As[kk][tr * 4 + i];
#pragma unroll
            for (int j = 0; j < 4; ++j) b[j] = Bs[kk][tc * 4 + j];
#pragma unroll
            for (int i = 0; i < 4; ++i)
#pragma unroll
                for (int j = 0; j < 4; ++j) acc[i][j] += a[i] * b[j];
        }
        __syncthreads();
    }
#pragma unroll
    for (int i = 0; i < 4; ++i) {
        const int row = row0 + tr * 4 + i;
        if (row < n) {
#pragma unroll
            for (int j = 0; j < 4; ++j)
                C[(size_t)row * m + col0 + tc * 4 + j] = acc[i][j];
        }
    }
}

// ------------- per-node attention coefficients a_src, a_dst ---------------
template <int H, int C>
__global__ void att_kernel(const float* __restrict__ h,
                           const float* __restrict__ att_s,
                           const float* __restrict__ att_d,
                           float* __restrict__ as_, float* __restrict__ ad_,
                           int n) {
    const int idx = blockIdx.x * blockDim.x + threadIdx.x;
    if (idx >= n * H) return;
    const int node = idx / H;
    const int hh = idx % H;
    const float* hp = h + (size_t)node * H * C + hh * C;
    float s0 = 0.f, s1 = 0.f;
#pragma unroll
    for (int c = 0; c < C; ++c) {
        const float v = hp[c];
        s0 += v * att_s[hh * C + c];
        s1 += v * att_d[hh * C + c];
    }
    as_[idx] = s0;
    ad_[idx] = s1;
}

// ----------------------------- CSR build ----------------------------------
__global__ void deg_kernel(const int* __restrict__ dst, int* __restrict__ deg,
                           int e) {
    const int i = blockIdx.x * blockDim.x + threadIdx.x;
    if (i < e) atomicAdd(&deg[dst[i]], 1);
}

__global__ __launch_bounds__(1024) void scan1_kernel(const int* __restrict__ deg,
                                                     int* __restrict__ offs,
                                                     int* __restrict__ sums,
                                                     int n) {
    __shared__ int s[1024];
    const int t = threadIdx.x;
    const int i = blockIdx.x * 1024 + t;
    const int v = (i < n) ? deg[i] : 0;
    s[t] = v;
    __syncthreads();
    for (int d = 1; d < 1024; d <<= 1) {
        const int x = (t >= d) ? s[t - d] : 0;
        __syncthreads();
        s[t] += x;
        __syncthreads();
    }
    if (i < n) offs[i] = s[t] - v;
    if (t == 1023) sums[blockIdx.x] = s[1023];
}

__global__ __launch_bounds__(128) void scan2_kernel(int* sums, int nb) {
    __shared__ int s[128];
    const int t = threadIdx.x;
    const int v = (t < nb) ? sums[t] : 0;
    s[t] = v;
    __syncthreads();
    for (int d = 1; d < 128; d <<= 1) {
        const int x = (t >= d) ? s[t - d] : 0;
        __syncthreads();
        s[t] += x;
        __syncthreads();
    }
    if (t < nb) sums[t] = s[t] - v;
}

__global__ __launch_bounds__(1024) void scan3_kernel(int* __restrict__ offs,
                                                     const int* __restrict__ sums,
                                                     int* __restrict__ cursor,
                                                     int n) {
    const int i = blockIdx.x * 1024 + threadIdx.x;
    if (i < n) {
        const int o = offs[i] + sums[blockIdx.x];
        offs[i] = o;
        cursor[i] = o;
    }
}

__global__ void fill_kernel(const int* __restrict__ src,
                            const int* __restrict__ dst, int* cursor,
                            int* __restrict__ csr, int e) {
    const int i = blockIdx.x * blockDim.x + threadIdx.x;
    if (i < e) {
        const int p = atomicAdd(&cursor[dst[i]], 1);
        csr[p] = src[i];
    }
}

// --------- single-pass gather-aggregate + fused softmax denominator -------
// One wave per dst node. Lane owns R consecutive channels (R*64 == H*C).
// No max-shift needed (|e| <= ~12): p = exp(lrelu(e)); denominator L
// accumulated per lane for head (lane & (H-1)); alpha broadcast by shuffle.
// Edge loop manually chunked by 8 with batched loads for memory-level
// parallelism (~16 outstanding loads/wave instead of 2).
template <int H, int C, bool DO_ELU>
__global__ __launch_bounds__(64) void agg_kernel(
    const float* __restrict__ h, const float* __restrict__ a_src,
    const float* __restrict__ a_dst, const int* __restrict__ csr,
    const int* __restrict__ offs, const int* __restrict__ deg,
    const float* __restrict__ bias, float* __restrict__ out, int n) {
    constexpr int HC = H * C;
    constexpr int R = HC / 64;  // 2 (layer1) or 1 (layer2)
    constexpr int U = 8;        // edge chunk size
    const int dst = blockIdx.x;
    const int lane = threadIdx.x;
    const int start = offs[dst];
    const int d = deg[dst];
    const int myh = lane & (H - 1);  // head whose alpha this lane computes
    const int ch0 = lane * R;        // first owned channel
    const int hh = ch0 / C;          // head of owned channels
    const float advm = a_dst[dst * H + myh];
    float acc0 = 0.f, acc1 = 0.f;
    float L = 0.f;

    // self loop (src = dst)
    {
        float e = a_src[dst * H + myh] + advm;
        e = fmaxf(e, 0.2f * e);
        const float p = __expf(e);
        L += p;
        const float a = (H > 1) ? __shfl(p, hh) : p;
        const float* hp = h + (size_t)dst * HC + ch0;
        if (R == 2) {
            const float2 v = *(const float2*)hp;
            acc0 += a * v.x;
            acc1 += a * v.y;
        } else {
            acc0 += a * hp[0];
        }
    }

    int j = 0;
    for (; j + U <= d; j += U) {
        int s[U];
        float es[U];
        float2 v2[U];
        float v1[U];
#pragma unroll
        for (int u = 0; u < U; ++u) s[u] = csr[start + j + u];
#pragma unroll
        for (int u = 0; u < U; ++u) es[u] = a_src[s[u] * H + myh];
#pragma unroll
        for (int u = 0; u < U; ++u) {
            const float* hp = h + (size_t)s[u] * HC + ch0;
            if (R == 2) v2[u] = *(const float2*)hp;
            else v1[u] = hp[0];
        }
#pragma unroll
        for (int u = 0; u < U; ++u) {
            float e = es[u] + advm;
            e = fmaxf(e, 0.2f * e);
            const float p = __expf(e);
            L += p;
            const float a = (H > 1) ? __shfl(p, hh) : p;
            if (R == 2) {
                acc0 += a * v2[u].x;
                acc1 += a * v2[u].y;
            } else {
                acc0 += a * v1[u];
            }
        }
    }
    for (; j < d; ++j) {
        const int src = csr[start + j];
        float e = a_src[src * H + myh] + advm;
        e = fmaxf(e, 0.2f * e);
        const float p = __expf(e);
        L += p;
        const float a = (H > 1) ? __shfl(p, hh) : p;
        const float* hp = h + (size_t)src * HC + ch0;
        if (R == 2) {
            const float2 v = *(const float2*)hp;
            acc0 += a * v.x;
            acc1 += a * v.y;
        } else {
            acc0 += a * hp[0];
        }
    }

    const float Ld = (H > 1) ? __shfl(L, hh) : L;
    const float linv = 1.f / (Ld + 1e-16f);
    float r0 = acc0 * linv + bias[ch0];
    if (DO_ELU) r0 = (r0 > 0.f) ? r0 : (__expf(r0) - 1.f);
    float* op = out + (size_t)dst * HC + ch0;
    if (R == 2) {
        float r1 = acc1 * linv + bias[ch0 + 1];
        if (DO_ELU) r1 = (r1 > 0.f) ? r1 : (__expf(r1) - 1.f);
        *(float2*)op = make_float2(r0, r1);
    } else {
        op[0] = r0;
    }
}

// --------------------------------------------------------------------------
extern "C" void kernel_launch(void* const* d_in, const int* in_sizes, int n_in,
                              void* d_out, int out_size, void* d_ws,
                              size_t ws_size, hipStream_t stream) {
    const float* x = (const float*)d_in[0];
    const int* ei = (const int*)d_in[1];
    const float* W1 = (const float*)d_in[2];
    const float* att_s1 = (const float*)d_in[3];
    const float* att_d1 = (const float*)d_in[4];
    const float* b1 = (const float*)d_in[5];
    const float* W2 = (const float*)d_in[6];
    const float* att_s2 = (const float*)d_in[7];
    const float* att_d2 = (const float*)d_in[8];
    const float* b2 = (const float*)d_in[9];

    const int N = in_sizes[0] / 256;  // 100000
    const int E = in_sizes[1] / 2;    // 1600000
    const int* srcp = ei;
    const int* dstp = ei + E;

    float* h1 = (float*)d_ws;            // N*128
    float* h1p = h1 + (size_t)N * 128;   // N*128
    float* as1 = h1p + (size_t)N * 128;  // N*4
    float* ad1 = as1 + (size_t)N * 4;    // N*4
    float* as2 = ad1 + (size_t)N * 4;    // N
    float* ad2 = as2 + N;                // N
    int* deg = (int*)(ad2 + N);          // N
    int* offs = deg + N;                 // N
    int* cursor = offs + N;              // N
    int* sums = cursor + N;              // 128
    int* csr = sums + 128;               // E
    float* h2 = h1;  // h1 dead after layer-1 aggregation

    const int nb = (N + 1023) / 1024;

    // ---- CSR build ----
    hipMemsetAsync(deg, 0, (size_t)N * 4, stream);
    deg_kernel<<<(E + 255) / 256, 256, 0, stream>>>(dstp, deg, E);
    scan1_kernel<<<nb, 1024, 0, stream>>>(deg, offs, sums, N);
    scan2_kernel<<<1, 128, 0, stream>>>(sums, nb);
    scan3_kernel<<<nb, 1024, 0, stream>>>(offs, sums, cursor, N);
    fill_kernel<<<(E + 255) / 256, 256, 0, stream>>>(srcp, dstp, cursor, csr, E);

    // ---- layer 1 ----
    {
        dim3 grid((N + 63) / 64, 128 / 64);
        gemm_kernel<<<grid, 256, 0, stream>>>(x, W1, h1, N, 256, 128);
    }
    att_kernel<4, 32><<<(N * 4 + 255) / 256, 256, 0, stream>>>(h1, att_s1,
                                                               att_d1, as1,
                                                               ad1, N);
    agg_kernel<4, 32, true><<<N, 64, 0, stream>>>(h1, as1, ad1, csr, offs, deg,
                                                  b1, h1p, N);

    // ---- layer 2 ----
    {
        dim3 grid((N + 63) / 64, 64 / 64);
        gemm_kernel<<<grid, 256, 0, stream>>>(h1p, W2, h2, N, 128, 64);
    }
    att_kernel<1, 64><<<(N + 255) / 256, 256, 0, stream>>>(h2, att_s2, att_d2,
                                                           as2, ad2, N);
    agg_kernel<1, 64, false><<<N, 64, 0, stream>>>(h2, as2, ad2, csr, offs,
                                                   deg, b2, (float*)d_out, N);
}

// Round 5
// 634.274 us; speedup vs baseline: 1.2616x; 1.1226x over previous
//
#include <hip/hip_runtime.h>
#include <math.h>

typedef unsigned short ushort_t;
typedef unsigned int uint_t;

__device__ __forceinline__ float bf16_to_f32(ushort_t u) {
    union { uint_t i; float f; } c;
    c.i = ((uint_t)u) << 16;
    return c.f;
}
__device__ __forceinline__ ushort_t f32_to_bf16(float f) {
    union { float f; uint_t i; } c;
    c.f = f;
    const uint_t x = c.i;
    return (ushort_t)((x + 0x7fffu + ((x >> 16) & 1u)) >> 16);
}

// ------- GEMM: C[N,M](bf16) = A[N,K](f32) * B[K,M](f32), row-major --------
__global__ __launch_bounds__(256) void gemm_kernel(const float* __restrict__ A,
                                                   const float* __restrict__ B,
                                                   ushort_t* __restrict__ C,
                                                   int n, int k, int m) {
    __shared__ float As[16][68];
    __shared__ float Bs[16][68];
    const int row0 = blockIdx.x * 64;
    const int col0 = blockIdx.y * 64;
    const int tid = threadIdx.x;
    const int tr = tid >> 4;
    const int tc = tid & 15;
    float acc[4][4] = {};
    for (int k0 = 0; k0 < k; k0 += 16) {
        {
            const int kk = tid & 15;
            const int mbase = tid >> 4;
#pragma unroll
            for (int i = 0; i < 4; ++i) {
                const int mm = mbase + i * 16;
                const int row = row0 + mm;
                As[kk][mm] = (row < n) ? A[(size_t)row * k + k0 + kk] : 0.f;
            }
        }
        {
            const int nn = tid & 63;
            const int kbase = tid >> 6;
#pragma unroll
            for (int i = 0; i < 4; ++i) {
                const int kk = kbase + i * 4;
                Bs[kk][nn] = B[(size_t)(k0 + kk) * m + col0 + nn];
            }
        }
        __syncthreads();
#pragma unroll
        for (int kk = 0; kk < 16; ++kk) {
            float a[4], b[4];
#pragma unroll
            for (int i = 0; i < 4; ++i) a[i] = As[kk][tr * 4 + i];
#pragma unroll
            for (int j = 0; j < 4; ++j) b[j] = Bs[kk][tc * 4 + j];
#pragma unroll
            for (int i = 0; i < 4; ++i)
#pragma unroll
                for (int j = 0; j < 4; ++j) acc[i][j] += a[i] * b[j];
        }
        __syncthreads();
    }
#pragma unroll
    for (int i = 0; i < 4; ++i) {
        const int row = row0 + tr * 4 + i;
        if (row < n) {
            ushort4 v;
            v.x = f32_to_bf16(acc[i][0]);
            v.y = f32_to_bf16(acc[i][1]);
            v.z = f32_to_bf16(acc[i][2]);
            v.w = f32_to_bf16(acc[i][3]);
            *(ushort4*)&C[(size_t)row * m + col0 + tc * 4] = v;
        }
    }
}

// ------------- per-node attention coefficients a_src, a_dst ---------------
template <int H, int C>
__global__ void att_kernel(const ushort_t* __restrict__ h,
                           const float* __restrict__ att_s,
                           const float* __restrict__ att_d,
                           float* __restrict__ as_, float* __restrict__ ad_,
                           int n) {
    const int idx = blockIdx.x * blockDim.x + threadIdx.x;
    if (idx >= n * H) return;
    const int node = idx / H;
    const int hh = idx % H;
    const ushort_t* hp = h + (size_t)node * H * C + hh * C;
    float s0 = 0.f, s1 = 0.f;
#pragma unroll
    for (int c = 0; c < C; ++c) {
        const float v = bf16_to_f32(hp[c]);
        s0 += v * att_s[hh * C + c];
        s1 += v * att_d[hh * C + c];
    }
    as_[idx] = s0;
    ad_[idx] = s1;
}

// ----------------------------- CSR build ----------------------------------
__global__ void deg_kernel(const int* __restrict__ dst, int* __restrict__ deg,
                           int e) {
    const int i = blockIdx.x * blockDim.x + threadIdx.x;
    if (i < e) atomicAdd(&deg[dst[i]], 1);
}

__global__ __launch_bounds__(1024) void scan1_kernel(const int* __restrict__ deg,
                                                     int* __restrict__ offs,
                                                     int* __restrict__ sums,
                                                     int n) {
    __shared__ int s[1024];
    const int t = threadIdx.x;
    const int i = blockIdx.x * 1024 + t;
    const int v = (i < n) ? deg[i] : 0;
    s[t] = v;
    __syncthreads();
    for (int d = 1; d < 1024; d <<= 1) {
        const int x = (t >= d) ? s[t - d] : 0;
        __syncthreads();
        s[t] += x;
        __syncthreads();
    }
    if (i < n) offs[i] = s[t] - v;
    if (t == 1023) sums[blockIdx.x] = s[1023];
}

__global__ __launch_bounds__(128) void scan2_kernel(int* sums, int nb) {
    __shared__ int s[128];
    const int t = threadIdx.x;
    const int v = (t < nb) ? sums[t] : 0;
    s[t] = v;
    __syncthreads();
    for (int d = 1; d < 128; d <<= 1) {
        const int x = (t >= d) ? s[t - d] : 0;
        __syncthreads();
        s[t] += x;
        __syncthreads();
    }
    if (t < nb) sums[t] = s[t] - v;
}

__global__ __launch_bounds__(1024) void scan3_kernel(int* __restrict__ offs,
                                                     const int* __restrict__ sums,
                                                     int* __restrict__ cursor,
                                                     int n) {
    const int i = blockIdx.x * 1024 + threadIdx.x;
    if (i < n) {
        const int o = offs[i] + sums[blockIdx.x];
        offs[i] = o;
        cursor[i] = o;
    }
}

__global__ void fill_kernel(const int* __restrict__ src,
                            const int* __restrict__ dst, int* cursor,
                            int* __restrict__ csr, int e) {
    const int i = blockIdx.x * blockDim.x + threadIdx.x;
    if (i < e) {
        const int p = atomicAdd(&cursor[dst[i]], 1);
        csr[p] = src[i];
    }
}

// --------- single-pass gather-aggregate + fused softmax denominator -------
// One wave per dst node. Lane owns R consecutive channels (R*64 == H*C).
// h table is bf16 (halved gather bytes); decode in-register.
template <int H, int C, bool DO_ELU>
__global__ __launch_bounds__(64) void agg_kernel(
    const ushort_t* __restrict__ h, const float* __restrict__ a_src,
    const float* __restrict__ a_dst, const int* __restrict__ csr,
    const int* __restrict__ offs, const int* __restrict__ deg,
    const float* __restrict__ bias, float* __restrict__ out, int n) {
    constexpr int HC = H * C;
    constexpr int R = HC / 64;  // 2 (layer1) or 1 (layer2)
    constexpr int U = 8;        // edge chunk size
    const int dst = blockIdx.x;
    const int lane = threadIdx.x;
    const int start = offs[dst];
    const int d = deg[dst];
    const int myh = lane & (H - 1);  // head whose alpha this lane computes
    const int ch0 = lane * R;        // first owned channel
    const int hh = ch0 / C;          // head of owned channels
    const float advm = a_dst[dst * H + myh];
    float acc0 = 0.f, acc1 = 0.f;
    float L = 0.f;

    // self loop (src = dst)
    {
        float e = a_src[dst * H + myh] + advm;
        e = fmaxf(e, 0.2f * e);
        const float p = __expf(e);
        L += p;
        const float a = (H > 1) ? __shfl(p, hh) : p;
        const ushort_t* hp = h + (size_t)dst * HC + ch0;
        if (R == 2) {
            const uint_t v = *(const uint_t*)hp;
            acc0 += a * bf16_to_f32((ushort_t)(v & 0xffffu));
            acc1 += a * bf16_to_f32((ushort_t)(v >> 16));
        } else {
            acc0 += a * bf16_to_f32(hp[0]);
        }
    }

    int j = 0;
    for (; j + U <= d; j += U) {
        int s[U];
        float es[U];
        uint_t hv[U];
#pragma unroll
        for (int u = 0; u < U; ++u) s[u] = csr[start + j + u];
#pragma unroll
        for (int u = 0; u < U; ++u) es[u] = a_src[s[u] * H + myh];
#pragma unroll
        for (int u = 0; u < U; ++u) {
            const ushort_t* hp = h + (size_t)s[u] * HC + ch0;
            if (R == 2) hv[u] = *(const uint_t*)hp;
            else hv[u] = (uint_t)hp[0];
        }
#pragma unroll
        for (int u = 0; u < U; ++u) {
            float e = es[u] + advm;
            e = fmaxf(e, 0.2f * e);
            const float p = __expf(e);
            L += p;
            const float a = (H > 1) ? __shfl(p, hh) : p;
            if (R == 2) {
                acc0 += a * bf16_to_f32((ushort_t)(hv[u] & 0xffffu));
                acc1 += a * bf16_to_f32((ushort_t)(hv[u] >> 16));
            } else {
                acc0 += a * bf16_to_f32((ushort_t)hv[u]);
            }
        }
    }
    for (; j < d; ++j) {
        const int src = csr[start + j];
        float e = a_src[src * H + myh] + advm;
        e = fmaxf(e, 0.2f * e);
        const float p = __expf(e);
        L += p;
        const float a = (H > 1) ? __shfl(p, hh) : p;
        const ushort_t* hp = h + (size_t)src * HC + ch0;
        if (R == 2) {
            const uint_t v = *(const uint_t*)hp;
            acc0 += a * bf16_to_f32((ushort_t)(v & 0xffffu));
            acc1 += a * bf16_to_f32((ushort_t)(v >> 16));
        } else {
            acc0 += a * bf16_to_f32(hp[0]);
        }
    }

    const float Ld = (H > 1) ? __shfl(L, hh) : L;
    const float linv = 1.f / (Ld + 1e-16f);
    float r0 = acc0 * linv + bias[ch0];
    if (DO_ELU) r0 = (r0 > 0.f) ? r0 : (__expf(r0) - 1.f);
    float* op = out + (size_t)dst * HC + ch0;
    if (R == 2) {
        float r1 = acc1 * linv + bias[ch0 + 1];
        if (DO_ELU) r1 = (r1 > 0.f) ? r1 : (__expf(r1) - 1.f);
        *(float2*)op = make_float2(r0, r1);
    } else {
        op[0] = r0;
    }
}

// --------------------------------------------------------------------------
extern "C" void kernel_launch(void* const* d_in, const int* in_sizes, int n_in,
                              void* d_out, int out_size, void* d_ws,
                              size_t ws_size, hipStream_t stream) {
    const float* x = (const float*)d_in[0];
    const int* ei = (const int*)d_in[1];
    const float* W1 = (const float*)d_in[2];
    const float* att_s1 = (const float*)d_in[3];
    const float* att_d1 = (const float*)d_in[4];
    const float* b1 = (const float*)d_in[5];
    const float* W2 = (const float*)d_in[6];
    const float* att_s2 = (const float*)d_in[7];
    const float* att_d2 = (const float*)d_in[8];
    const float* b2 = (const float*)d_in[9];

    const int N = in_sizes[0] / 256;  // 100000
    const int E = in_sizes[1] / 2;    // 1600000
    const int* srcp = ei;
    const int* dstp = ei + E;

    // workspace layout: f32 arrays, then ints, then bf16 tables
    float* h1p = (float*)d_ws;           // N*128 f32 (agg1 out, gemm2 A)
    float* as1 = h1p + (size_t)N * 128;  // N*4
    float* ad1 = as1 + (size_t)N * 4;    // N*4
    float* as2 = ad1 + (size_t)N * 4;    // N
    float* ad2 = as2 + N;                // N
    int* deg = (int*)(ad2 + N);          // N
    int* offs = deg + N;                 // N
    int* cursor = offs + N;              // N
    int* sums = cursor + N;              // 128
    int* csr = sums + 128;               // E
    ushort_t* h1 = (ushort_t*)(csr + E); // N*128 bf16 (gemm1 out, gathered)
    ushort_t* h2 = h1 + (size_t)N * 128; // N*64 bf16 (gemm2 out, gathered)

    const int nb = (N + 1023) / 1024;

    // ---- CSR build ----
    hipMemsetAsync(deg, 0, (size_t)N * 4, stream);
    deg_kernel<<<(E + 255) / 256, 256, 0, stream>>>(dstp, deg, E);
    scan1_kernel<<<nb, 1024, 0, stream>>>(deg, offs, sums, N);
    scan2_kernel<<<1, 128, 0, stream>>>(sums, nb);
    scan3_kernel<<<nb, 1024, 0, stream>>>(offs, sums, cursor, N);
    fill_kernel<<<(E + 255) / 256, 256, 0, stream>>>(srcp, dstp, cursor, csr, E);

    // ---- layer 1 ----
    {
        dim3 grid((N + 63) / 64, 128 / 64);
        gemm_kernel<<<grid, 256, 0, stream>>>(x, W1, h1, N, 256, 128);
    }
    att_kernel<4, 32><<<(N * 4 + 255) / 256, 256, 0, stream>>>(h1, att_s1,
                                                               att_d1, as1,
                                                               ad1, N);
    agg_kernel<4, 32, true><<<N, 64, 0, stream>>>(h1, as1, ad1, csr, offs, deg,
                                                  b1, h1p, N);

    // ---- layer 2 ----
    {
        dim3 grid((N + 63) / 64, 64 / 64);
        gemm_kernel<<<grid, 256, 0, stream>>>(h1p, W2, h2, N, 128, 64);
    }
    att_kernel<1, 64><<<(N + 255) / 256, 256, 0, stream>>>(h2, att_s2, att_d2,
                                                           as2, ad2, N);
    agg_kernel<1, 64, false><<<N, 64, 0, stream>>>(h2, as2, ad2, csr, offs,
                                                   deg, b2, (float*)d_out, N);
}

// Round 6
// 559.826 us; speedup vs baseline: 1.4294x; 1.1330x over previous
//
#include <hip/hip_runtime.h>
#include <math.h>

typedef unsigned short ushort_t;
typedef unsigned int uint_t;

__device__ __forceinline__ float bf16_to_f32(ushort_t u) {
    union { uint_t i; float f; } c;
    c.i = ((uint_t)u) << 16;
    return c.f;
}
__device__ __forceinline__ ushort_t f32_to_bf16(float f) {
    union { float f; uint_t i; } c;
    c.f = f;
    const uint_t x = c.i;
    return (ushort_t)((x + 0x7fffu + ((x >> 16) & 1u)) >> 16);
}

// ---- GEMM device body: C[N,M](bf16) = A[N,K](f32)*B[K,M](f32), 64x64 tile -
__device__ __forceinline__ void gemm_body(const float* __restrict__ A,
                                          const float* __restrict__ B,
                                          ushort_t* __restrict__ C, int n,
                                          int k, int m, int row0, int col0,
                                          float As[16][68], float Bs[16][68]) {
    const int tid = threadIdx.x;
    const int tr = tid >> 4;
    const int tc = tid & 15;
    float acc[4][4] = {};
    for (int k0 = 0; k0 < k; k0 += 16) {
        {
            const int kk = tid & 15;
            const int mbase = tid >> 4;
#pragma unroll
            for (int i = 0; i < 4; ++i) {
                const int mm = mbase + i * 16;
                const int row = row0 + mm;
                As[kk][mm] = (row < n) ? A[(size_t)row * k + k0 + kk] : 0.f;
            }
        }
        {
            const int nn = tid & 63;
            const int kbase = tid >> 6;
#pragma unroll
            for (int i = 0; i < 4; ++i) {
                const int kk = kbase + i * 4;
                Bs[kk][nn] = B[(size_t)(k0 + kk) * m + col0 + nn];
            }
        }
        __syncthreads();
#pragma unroll
        for (int kk = 0; kk < 16; ++kk) {
            float a[4], b[4];
#pragma unroll
            for (int i = 0; i < 4; ++i) a[i] = As[kk][tr * 4 + i];
#pragma unroll
            for (int j = 0; j < 4; ++j) b[j] = Bs[kk][tc * 4 + j];
#pragma unroll
            for (int i = 0; i < 4; ++i)
#pragma unroll
                for (int j = 0; j < 4; ++j) acc[i][j] += a[i] * b[j];
        }
        __syncthreads();
    }
#pragma unroll
    for (int i = 0; i < 4; ++i) {
        const int row = row0 + tr * 4 + i;
        if (row < n) {
            ushort4 v;
            v.x = f32_to_bf16(acc[i][0]);
            v.y = f32_to_bf16(acc[i][1]);
            v.z = f32_to_bf16(acc[i][2]);
            v.w = f32_to_bf16(acc[i][3]);
            *(ushort4*)&C[(size_t)row * m + col0 + tc * 4] = v;
        }
    }
}

// ---- plain GEMM kernel (layer 2) ----
__global__ __launch_bounds__(256) void gemm_kernel(const float* __restrict__ A,
                                                   const float* __restrict__ B,
                                                   ushort_t* __restrict__ C,
                                                   int n, int k, int m) {
    __shared__ float As[16][68];
    __shared__ float Bs[16][68];
    gemm_body(A, B, C, n, k, m, blockIdx.x * 64, blockIdx.y * 64, As, Bs);
}

// ---- fused: layer-1 GEMM (m==128, 2 col-blocks) + CSR fill ---------------
// Fill blocks are latency-bound with idle VALU; GEMM blocks are VALU-bound
// with little memory traffic — co-resident on the same CUs they overlap.
__global__ __launch_bounds__(256) void gemm1_fill_kernel(
    const float* __restrict__ A, const float* __restrict__ B,
    ushort_t* __restrict__ C, int n, int k, int nblk_gemm,
    const int* __restrict__ src, const int* __restrict__ dst, int* cursor,
    int* __restrict__ csr, int e) {
    __shared__ float As[16][68];
    __shared__ float Bs[16][68];
    const int bx = blockIdx.x;
    if (bx < nblk_gemm) {
        gemm_body(A, B, C, n, k, 128, (bx >> 1) * 64, (bx & 1) * 64, As, Bs);
    } else {
        const int i = (bx - nblk_gemm) * 256 + threadIdx.x;
        if (i < e) {
            const int p = atomicAdd(&cursor[dst[i]], 1);
            csr[p] = src[i];
        }
    }
}

// ------------- per-node attention coefficients a_src, a_dst ---------------
template <int H, int C>
__global__ void att_kernel(const ushort_t* __restrict__ h,
                           const float* __restrict__ att_s,
                           const float* __restrict__ att_d,
                           float* __restrict__ as_, float* __restrict__ ad_,
                           int n) {
    const int idx = blockIdx.x * blockDim.x + threadIdx.x;
    if (idx >= n * H) return;
    const int node = idx / H;
    const int hh = idx % H;
    const ushort_t* hp = h + (size_t)node * H * C + hh * C;
    float s0 = 0.f, s1 = 0.f;
#pragma unroll
    for (int c = 0; c < C; ++c) {
        const float v = bf16_to_f32(hp[c]);
        s0 += v * att_s[hh * C + c];
        s1 += v * att_d[hh * C + c];
    }
    as_[idx] = s0;
    ad_[idx] = s1;
}

// ----------------------------- CSR build ----------------------------------
__global__ void deg_kernel(const int* __restrict__ dst, int* __restrict__ deg,
                           int e) {
    const int i = blockIdx.x * blockDim.x + threadIdx.x;
    if (i < e) atomicAdd(&deg[dst[i]], 1);
}

__global__ __launch_bounds__(1024) void scan1_kernel(const int* __restrict__ deg,
                                                     int* __restrict__ offs,
                                                     int* __restrict__ sums,
                                                     int n) {
    __shared__ int s[1024];
    const int t = threadIdx.x;
    const int i = blockIdx.x * 1024 + t;
    const int v = (i < n) ? deg[i] : 0;
    s[t] = v;
    __syncthreads();
    for (int d = 1; d < 1024; d <<= 1) {
        const int x = (t >= d) ? s[t - d] : 0;
        __syncthreads();
        s[t] += x;
        __syncthreads();
    }
    if (i < n) offs[i] = s[t] - v;
    if (t == 1023) sums[blockIdx.x] = s[1023];
}

__global__ __launch_bounds__(128) void scan2_kernel(int* sums, int nb) {
    __shared__ int s[128];
    const int t = threadIdx.x;
    const int v = (t < nb) ? sums[t] : 0;
    s[t] = v;
    __syncthreads();
    for (int d = 1; d < 128; d <<= 1) {
        const int x = (t >= d) ? s[t - d] : 0;
        __syncthreads();
        s[t] += x;
        __syncthreads();
    }
    if (t < nb) sums[t] = s[t] - v;
}

__global__ __launch_bounds__(1024) void scan3_kernel(int* __restrict__ offs,
                                                     const int* __restrict__ sums,
                                                     int* __restrict__ cursor,
                                                     int n) {
    const int i = blockIdx.x * 1024 + threadIdx.x;
    if (i < n) {
        const int o = offs[i] + sums[blockIdx.x];
        offs[i] = o;
        cursor[i] = o;
    }
}

// --------- single-pass gather-aggregate + fused softmax denominator -------
template <int H, int C, bool DO_ELU>
__global__ __launch_bounds__(64) void agg_kernel(
    const ushort_t* __restrict__ h, const float* __restrict__ a_src,
    const float* __restrict__ a_dst, const int* __restrict__ csr,
    const int* __restrict__ offs, const int* __restrict__ deg,
    const float* __restrict__ bias, float* __restrict__ out, int n) {
    constexpr int HC = H * C;
    constexpr int R = HC / 64;  // 2 (layer1) or 1 (layer2)
    constexpr int U = 8;        // edge chunk size
    const int dst = blockIdx.x;
    const int lane = threadIdx.x;
    const int start = offs[dst];
    const int d = deg[dst];
    const int myh = lane & (H - 1);
    const int ch0 = lane * R;
    const int hh = ch0 / C;
    const float advm = a_dst[dst * H + myh];
    float acc0 = 0.f, acc1 = 0.f;
    float L = 0.f;

    {
        float e = a_src[dst * H + myh] + advm;
        e = fmaxf(e, 0.2f * e);
        const float p = __expf(e);
        L += p;
        const float a = (H > 1) ? __shfl(p, hh) : p;
        const ushort_t* hp = h + (size_t)dst * HC + ch0;
        if (R == 2) {
            const uint_t v = *(const uint_t*)hp;
            acc0 += a * bf16_to_f32((ushort_t)(v & 0xffffu));
            acc1 += a * bf16_to_f32((ushort_t)(v >> 16));
        } else {
            acc0 += a * bf16_to_f32(hp[0]);
        }
    }

    int j = 0;
    for (; j + U <= d; j += U) {
        int s[U];
        float es[U];
        uint_t hv[U];
#pragma unroll
        for (int u = 0; u < U; ++u) s[u] = csr[start + j + u];
#pragma unroll
        for (int u = 0; u < U; ++u) es[u] = a_src[s[u] * H + myh];
#pragma unroll
        for (int u = 0; u < U; ++u) {
            const ushort_t* hp = h + (size_t)s[u] * HC + ch0;
            if (R == 2) hv[u] = *(const uint_t*)hp;
            else hv[u] = (uint_t)hp[0];
        }
#pragma unroll
        for (int u = 0; u < U; ++u) {
            float e = es[u] + advm;
            e = fmaxf(e, 0.2f * e);
            const float p = __expf(e);
            L += p;
            const float a = (H > 1) ? __shfl(p, hh) : p;
            if (R == 2) {
                acc0 += a * bf16_to_f32((ushort_t)(hv[u] & 0xffffu));
                acc1 += a * bf16_to_f32((ushort_t)(hv[u] >> 16));
            } else {
                acc0 += a * bf16_to_f32((ushort_t)hv[u]);
            }
        }
    }
    for (; j < d; ++j) {
        const int src = csr[start + j];
        float e = a_src[src * H + myh] + advm;
        e = fmaxf(e, 0.2f * e);
        const float p = __expf(e);
        L += p;
        const float a = (H > 1) ? __shfl(p, hh) : p;
        const ushort_t* hp = h + (size_t)src * HC + ch0;
        if (R == 2) {
            const uint_t v = *(const uint_t*)hp;
            acc0 += a * bf16_to_f32((ushort_t)(v & 0xffffu));
            acc1 += a * bf16_to_f32((ushort_t)(v >> 16));
        } else {
            acc0 += a * bf16_to_f32(hp[0]);
        }
    }

    const float Ld = (H > 1) ? __shfl(L, hh) : L;
    const float linv = 1.f / (Ld + 1e-16f);
    float r0 = acc0 * linv + bias[ch0];
    if (DO_ELU) r0 = (r0 > 0.f) ? r0 : (__expf(r0) - 1.f);
    float* op = out + (size_t)dst * HC + ch0;
    if (R == 2) {
        float r1 = acc1 * linv + bias[ch0 + 1];
        if (DO_ELU) r1 = (r1 > 0.f) ? r1 : (__expf(r1) - 1.f);
        *(float2*)op = make_float2(r0, r1);
    } else {
        op[0] = r0;
    }
}

// --------------------------------------------------------------------------
extern "C" void kernel_launch(void* const* d_in, const int* in_sizes, int n_in,
                              void* d_out, int out_size, void* d_ws,
                              size_t ws_size, hipStream_t stream) {
    const float* x = (const float*)d_in[0];
    const int* ei = (const int*)d_in[1];
    const float* W1 = (const float*)d_in[2];
    const float* att_s1 = (const float*)d_in[3];
    const float* att_d1 = (const float*)d_in[4];
    const float* b1 = (const float*)d_in[5];
    const float* W2 = (const float*)d_in[6];
    const float* att_s2 = (const float*)d_in[7];
    const float* att_d2 = (const float*)d_in[8];
    const float* b2 = (const float*)d_in[9];

    const int N = in_sizes[0] / 256;  // 100000
    const int E = in_sizes[1] / 2;    // 1600000
    const int* srcp = ei;
    const int* dstp = ei + E;

    float* h1p = (float*)d_ws;           // N*128 f32 (agg1 out, gemm2 A)
    float* as1 = h1p + (size_t)N * 128;  // N*4
    float* ad1 = as1 + (size_t)N * 4;    // N*4
    float* as2 = ad1 + (size_t)N * 4;    // N
    float* ad2 = as2 + N;                // N
    int* deg = (int*)(ad2 + N);          // N
    int* offs = deg + N;                 // N
    int* cursor = offs + N;              // N
    int* sums = cursor + N;              // 128
    int* csr = sums + 128;               // E
    ushort_t* h1 = (ushort_t*)(csr + E); // N*128 bf16
    ushort_t* h2 = h1 + (size_t)N * 128; // N*64 bf16

    const int nb = (N + 1023) / 1024;

    // ---- CSR degree + offsets ----
    hipMemsetAsync(deg, 0, (size_t)N * 4, stream);
    deg_kernel<<<(E + 255) / 256, 256, 0, stream>>>(dstp, deg, E);
    scan1_kernel<<<nb, 1024, 0, stream>>>(deg, offs, sums, N);
    scan2_kernel<<<1, 128, 0, stream>>>(sums, nb);
    scan3_kernel<<<nb, 1024, 0, stream>>>(offs, sums, cursor, N);

    // ---- fused layer-1 GEMM + CSR fill ----
    {
        const int nblk_gemm = ((N + 63) / 64) * 2;      // 3126
        const int nblk_fill = (E + 255) / 256;          // 6250
        gemm1_fill_kernel<<<nblk_gemm + nblk_fill, 256, 0, stream>>>(
            x, W1, h1, N, 256, nblk_gemm, srcp, dstp, cursor, csr, E);
    }
    att_kernel<4, 32><<<(N * 4 + 255) / 256, 256, 0, stream>>>(h1, att_s1,
                                                               att_d1, as1,
                                                               ad1, N);
    agg_kernel<4, 32, true><<<N, 64, 0, stream>>>(h1, as1, ad1, csr, offs, deg,
                                                  b1, h1p, N);

    // ---- layer 2 ----
    {
        dim3 grid((N + 63) / 64, 64 / 64);
        gemm_kernel<<<grid, 256, 0, stream>>>(h1p, W2, h2, N, 128, 64);
    }
    att_kernel<1, 64><<<(N + 255) / 256, 256, 0, stream>>>(h2, att_s2, att_d2,
                                                           as2, ad2, N);
    agg_kernel<1, 64, false><<<N, 64, 0, stream>>>(h2, as2, ad2, csr, offs,
                                                   deg, b2, (float*)d_out, N);
}

// Round 7
// 500.272 us; speedup vs baseline: 1.5996x; 1.1190x over previous
//
#include <hip/hip_runtime.h>
#include <math.h>

typedef unsigned short ushort_t;
typedef unsigned int uint_t;

__device__ __forceinline__ float bf16_to_f32(ushort_t u) {
    union { uint_t i; float f; } c;
    c.i = ((uint_t)u) << 16;
    return c.f;
}
__device__ __forceinline__ ushort_t f32_to_bf16(float f) {
    union { float f; uint_t i; } c;
    c.f = f;
    const uint_t x = c.i;
    return (ushort_t)((x + 0x7fffu + ((x >> 16) & 1u)) >> 16);
}

// ------- GEMM: C[N,M](bf16) = A[N,K](f32) * B[K,M](f32), row-major --------
__global__ __launch_bounds__(256) void gemm_kernel(const float* __restrict__ A,
                                                   const float* __restrict__ B,
                                                   ushort_t* __restrict__ C,
                                                   int n, int k, int m) {
    __shared__ float As[16][68];
    __shared__ float Bs[16][68];
    const int row0 = blockIdx.x * 64;
    const int col0 = blockIdx.y * 64;
    const int tid = threadIdx.x;
    const int tr = tid >> 4;
    const int tc = tid & 15;
    float acc[4][4] = {};
    for (int k0 = 0; k0 < k; k0 += 16) {
        {
            const int kk = tid & 15;
            const int mbase = tid >> 4;
#pragma unroll
            for (int i = 0; i < 4; ++i) {
                const int mm = mbase + i * 16;
                const int row = row0 + mm;
                As[kk][mm] = (row < n) ? A[(size_t)row * k + k0 + kk] : 0.f;
            }
        }
        {
            const int nn = tid & 63;
            const int kbase = tid >> 6;
#pragma unroll
            for (int i = 0; i < 4; ++i) {
                const int kk = kbase + i * 4;
                Bs[kk][nn] = B[(size_t)(k0 + kk) * m + col0 + nn];
            }
        }
        __syncthreads();
#pragma unroll
        for (int kk = 0; kk < 16; ++kk) {
            float a[4], b[4];
#pragma unroll
            for (int i = 0; i < 4; ++i) a[i] = As[kk][tr * 4 + i];
#pragma unroll
            for (int j = 0; j < 4; ++j) b[j] = Bs[kk][tc * 4 + j];
#pragma unroll
            for (int i = 0; i < 4; ++i)
#pragma unroll
                for (int j = 0; j < 4; ++j) acc[i][j] += a[i] * b[j];
        }
        __syncthreads();
    }
#pragma unroll
    for (int i = 0; i < 4; ++i) {
        const int row = row0 + tr * 4 + i;
        if (row < n) {
            ushort4 v;
            v.x = f32_to_bf16(acc[i][0]);
            v.y = f32_to_bf16(acc[i][1]);
            v.z = f32_to_bf16(acc[i][2]);
            v.w = f32_to_bf16(acc[i][3]);
            *(ushort4*)&C[(size_t)row * m + col0 + tc * 4] = v;
        }
    }
}

// ------------- per-node attention coefficients a_src, a_dst ---------------
template <int H, int C>
__global__ void att_kernel(const ushort_t* __restrict__ h,
                           const float* __restrict__ att_s,
                           const float* __restrict__ att_d,
                           float* __restrict__ as_, float* __restrict__ ad_,
                           int n) {
    const int idx = blockIdx.x * blockDim.x + threadIdx.x;
    if (idx >= n * H) return;
    const int node = idx / H;
    const int hh = idx % H;
    const ushort_t* hp = h + (size_t)node * H * C + hh * C;
    float s0 = 0.f, s1 = 0.f;
#pragma unroll
    for (int c = 0; c < C; ++c) {
        const float v = bf16_to_f32(hp[c]);
        s0 += v * att_s[hh * C + c];
        s1 += v * att_d[hh * C + c];
    }
    as_[idx] = s0;
    ad_[idx] = s1;
}

// ------------------- CSR build via binned counting sort -------------------
// Buckets of 256 consecutive dst nodes (bucket = dst >> 8). All random
// accesses (histogram, cursors, degree count, rank assignment) live in LDS;
// global reads/writes are (near-)coalesced contiguous runs.

// K1: per-(bucket, block) histogram. histG[b*G + g].
__global__ __launch_bounds__(1024) void hist_kernel(const int* __restrict__ dst,
                                                    int* __restrict__ histG,
                                                    int e, int chunk, int NB,
                                                    int G) {
    __shared__ int hl[512];
    for (int b = threadIdx.x; b < NB; b += 1024) hl[b] = 0;
    __syncthreads();
    const int g = blockIdx.x;
    const int lo = g * chunk;
    const int hi = min(lo + chunk, e);
    for (int i = lo + threadIdx.x; i < hi; i += 1024)
        atomicAdd(&hl[dst[i] >> 8], 1);
    __syncthreads();
    for (int b = threadIdx.x; b < NB; b += 1024) histG[b * G + g] = hl[b];
}

// scan kernels (generic exclusive scan, up to 128*1024 elements)
__global__ __launch_bounds__(1024) void scan1_kernel(const int* __restrict__ in,
                                                     int* __restrict__ out,
                                                     int* __restrict__ sums,
                                                     int n) {
    __shared__ int s[1024];
    const int t = threadIdx.x;
    const int i = blockIdx.x * 1024 + t;
    const int v = (i < n) ? in[i] : 0;
    s[t] = v;
    __syncthreads();
    for (int d = 1; d < 1024; d <<= 1) {
        const int x = (t >= d) ? s[t - d] : 0;
        __syncthreads();
        s[t] += x;
        __syncthreads();
    }
    if (i < n) out[i] = s[t] - v;
    if (t == 1023) sums[blockIdx.x] = s[1023];
}

__global__ __launch_bounds__(128) void scan2_kernel(int* sums, int nb) {
    __shared__ int s[128];
    const int t = threadIdx.x;
    const int v = (t < nb) ? sums[t] : 0;
    s[t] = v;
    __syncthreads();
    for (int d = 1; d < 128; d <<= 1) {
        const int x = (t >= d) ? s[t - d] : 0;
        __syncthreads();
        s[t] += x;
        __syncthreads();
    }
    if (t < nb) sums[t] = s[t] - v;
}

__global__ __launch_bounds__(1024) void scan3_kernel(int* __restrict__ out,
                                                     const int* __restrict__ sums,
                                                     int n) {
    const int i = blockIdx.x * 1024 + threadIdx.x;
    if (i < n) out[i] += sums[blockIdx.x];
}

// K3: scatter (src,dst) pairs into bucket regions; cursors in LDS.
__global__ __launch_bounds__(1024) void bin_kernel(const int* __restrict__ src,
                                                   const int* __restrict__ dst,
                                                   const int* __restrict__ base,
                                                   int2* __restrict__ binned,
                                                   int e, int chunk, int NB,
                                                   int G) {
    __shared__ int cur[512];
    const int g = blockIdx.x;
    for (int b = threadIdx.x; b < NB; b += 1024) cur[b] = base[b * G + g];
    __syncthreads();
    const int lo = g * chunk;
    const int hi = min(lo + chunk, e);
    for (int i = lo + threadIdx.x; i < hi; i += 1024) {
        const int d = dst[i];
        const int p = atomicAdd(&cur[d >> 8], 1);
        binned[p] = make_int2(src[i], d);
    }
}

// K4: one block per bucket — LDS-local degree/scan/rank, contiguous csr out.
#define BUILD_CAP 6144
__global__ __launch_bounds__(256) void build_kernel(
    const int2* __restrict__ binned, const int* __restrict__ base,
    int* __restrict__ csr, int* __restrict__ deg, int* __restrict__ offs,
    int e, int n, int NB, int G) {
    __shared__ int2 ep[BUILD_CAP];
    __shared__ int degL[256];
    __shared__ int offL[256];
    __shared__ int curL[256];
    const int b = blockIdx.x;
    const int tid = threadIdx.x;
    const int start = base[b * G];
    const int end = (b == NB - 1) ? e : base[(b + 1) * G];
    const int cnt = end - start;
    const bool stage = (cnt <= BUILD_CAP);
    degL[tid] = 0;
    if (stage)
        for (int i = tid; i < cnt; i += 256) ep[i] = binned[start + i];
    __syncthreads();
    if (stage) {
        for (int i = tid; i < cnt; i += 256) atomicAdd(&degL[ep[i].y & 255], 1);
    } else {
        for (int i = tid; i < cnt; i += 256)
            atomicAdd(&degL[binned[start + i].y & 255], 1);
    }
    __syncthreads();
    const int v = degL[tid];
    offL[tid] = v;
    __syncthreads();
    for (int d = 1; d < 256; d <<= 1) {
        const int x = (tid >= d) ? offL[tid - d] : 0;
        __syncthreads();
        offL[tid] += x;
        __syncthreads();
    }
    const int excl = offL[tid] - v;
    curL[tid] = excl;
    const int node = (b << 8) + tid;
    if (node < n) {
        deg[node] = v;
        offs[node] = start + excl;
    }
    __syncthreads();
    if (stage) {
        for (int i = tid; i < cnt; i += 256) {
            const int p = atomicAdd(&curL[ep[i].y & 255], 1);
            csr[start + p] = ep[i].x;
        }
    } else {
        for (int i = tid; i < cnt; i += 256) {
            const int2 pr = binned[start + i];
            const int p = atomicAdd(&curL[pr.y & 255], 1);
            csr[start + p] = pr.x;
        }
    }
}

// --------- single-pass gather-aggregate + fused softmax denominator -------
template <int H, int C, bool DO_ELU>
__global__ __launch_bounds__(64) void agg_kernel(
    const ushort_t* __restrict__ h, const float* __restrict__ a_src,
    const float* __restrict__ a_dst, const int* __restrict__ csr,
    const int* __restrict__ offs, const int* __restrict__ deg,
    const float* __restrict__ bias, float* __restrict__ out, int n) {
    constexpr int HC = H * C;
    constexpr int R = HC / 64;  // 2 (layer1) or 1 (layer2)
    constexpr int U = 8;        // edge chunk size
    const int dst = blockIdx.x;
    const int lane = threadIdx.x;
    const int start = offs[dst];
    const int d = deg[dst];
    const int myh = lane & (H - 1);
    const int ch0 = lane * R;
    const int hh = ch0 / C;
    const float advm = a_dst[dst * H + myh];
    float acc0 = 0.f, acc1 = 0.f;
    float L = 0.f;

    {
        float e = a_src[dst * H + myh] + advm;
        e = fmaxf(e, 0.2f * e);
        const float p = __expf(e);
        L += p;
        const float a = (H > 1) ? __shfl(p, hh) : p;
        const ushort_t* hp = h + (size_t)dst * HC + ch0;
        if (R == 2) {
            const uint_t v = *(const uint_t*)hp;
            acc0 += a * bf16_to_f32((ushort_t)(v & 0xffffu));
            acc1 += a * bf16_to_f32((ushort_t)(v >> 16));
        } else {
            acc0 += a * bf16_to_f32(hp[0]);
        }
    }

    int j = 0;
    for (; j + U <= d; j += U) {
        int s[U];
        float es[U];
        uint_t hv[U];
#pragma unroll
        for (int u = 0; u < U; ++u) s[u] = csr[start + j + u];
#pragma unroll
        for (int u = 0; u < U; ++u) es[u] = a_src[s[u] * H + myh];
#pragma unroll
        for (int u = 0; u < U; ++u) {
            const ushort_t* hp = h + (size_t)s[u] * HC + ch0;
            if (R == 2) hv[u] = *(const uint_t*)hp;
            else hv[u] = (uint_t)hp[0];
        }
#pragma unroll
        for (int u = 0; u < U; ++u) {
            float e = es[u] + advm;
            e = fmaxf(e, 0.2f * e);
            const float p = __expf(e);
            L += p;
            const float a = (H > 1) ? __shfl(p, hh) : p;
            if (R == 2) {
                acc0 += a * bf16_to_f32((ushort_t)(hv[u] & 0xffffu));
                acc1 += a * bf16_to_f32((ushort_t)(hv[u] >> 16));
            } else {
                acc0 += a * bf16_to_f32((ushort_t)hv[u]);
            }
        }
    }
    for (; j < d; ++j) {
        const int src = csr[start + j];
        float e = a_src[src * H + myh] + advm;
        e = fmaxf(e, 0.2f * e);
        const float p = __expf(e);
        L += p;
        const float a = (H > 1) ? __shfl(p, hh) : p;
        const ushort_t* hp = h + (size_t)src * HC + ch0;
        if (R == 2) {
            const uint_t v = *(const uint_t*)hp;
            acc0 += a * bf16_to_f32((ushort_t)(v & 0xffffu));
            acc1 += a * bf16_to_f32((ushort_t)(v >> 16));
        } else {
            acc0 += a * bf16_to_f32(hp[0]);
        }
    }

    const float Ld = (H > 1) ? __shfl(L, hh) : L;
    const float linv = 1.f / (Ld + 1e-16f);
    float r0 = acc0 * linv + bias[ch0];
    if (DO_ELU) r0 = (r0 > 0.f) ? r0 : (__expf(r0) - 1.f);
    float* op = out + (size_t)dst * HC + ch0;
    if (R == 2) {
        float r1 = acc1 * linv + bias[ch0 + 1];
        if (DO_ELU) r1 = (r1 > 0.f) ? r1 : (__expf(r1) - 1.f);
        *(float2*)op = make_float2(r0, r1);
    } else {
        op[0] = r0;
    }
}

// --------------------------------------------------------------------------
extern "C" void kernel_launch(void* const* d_in, const int* in_sizes, int n_in,
                              void* d_out, int out_size, void* d_ws,
                              size_t ws_size, hipStream_t stream) {
    const float* x = (const float*)d_in[0];
    const int* ei = (const int*)d_in[1];
    const float* W1 = (const float*)d_in[2];
    const float* att_s1 = (const float*)d_in[3];
    const float* att_d1 = (const float*)d_in[4];
    const float* b1 = (const float*)d_in[5];
    const float* W2 = (const float*)d_in[6];
    const float* att_s2 = (const float*)d_in[7];
    const float* att_d2 = (const float*)d_in[8];
    const float* b2 = (const float*)d_in[9];

    const int N = in_sizes[0] / 256;  // 100000
    const int E = in_sizes[1] / 2;    // 1600000
    const int* srcp = ei;
    const int* dstp = ei + E;

    const int NB = (N + 255) >> 8;  // 391 buckets of 256 nodes
    const int G = 128;              // hist/bin blocks
    const int NBG = NB * G;         // 50048
    const int chunk = (E + G - 1) / G;
    const int nbs = (NBG + 1023) / 1024;  // scan blocks (49)

    // workspace layout
    float* h1p = (float*)d_ws;           // N*128 f32 (agg1 out, gemm2 A)
    float* as1 = h1p + (size_t)N * 128;  // N*4
    float* ad1 = as1 + (size_t)N * 4;    // N*4
    float* as2 = ad1 + (size_t)N * 4;    // N
    float* ad2 = as2 + N;                // N
    int* histG = (int*)(ad2 + N);        // NBG
    int* base = histG + NBG;             // NBG
    int* sums = base + NBG;              // 128
    int* deg = sums + 128;               // N
    int* offs = deg + N;                 // N
    int* csr = offs + N;                 // E
    int2* binned = (int2*)(csr + E);     // E pairs (dead after build)
    ushort_t* h1 = (ushort_t*)binned;    // N*128 bf16 (overlays binned)
    ushort_t* h2 = h1 + (size_t)N * 128; // N*64 bf16

    // ---- CSR build (binned counting sort, no global atomics) ----
    hist_kernel<<<G, 1024, 0, stream>>>(dstp, histG, E, chunk, NB, G);
    scan1_kernel<<<nbs, 1024, 0, stream>>>(histG, base, sums, NBG);
    scan2_kernel<<<1, 128, 0, stream>>>(sums, nbs);
    scan3_kernel<<<nbs, 1024, 0, stream>>>(base, sums, NBG);
    bin_kernel<<<G, 1024, 0, stream>>>(srcp, dstp, base, binned, E, chunk, NB,
                                       G);
    build_kernel<<<NB, 256, 0, stream>>>(binned, base, csr, deg, offs, E, N,
                                         NB, G);

    // ---- layer 1 ----
    {
        dim3 grid((N + 63) / 64, 128 / 64);
        gemm_kernel<<<grid, 256, 0, stream>>>(x, W1, h1, N, 256, 128);
    }
    att_kernel<4, 32><<<(N * 4 + 255) / 256, 256, 0, stream>>>(h1, att_s1,
                                                               att_d1, as1,
                                                               ad1, N);
    agg_kernel<4, 32, true><<<N, 64, 0, stream>>>(h1, as1, ad1, csr, offs, deg,
                                                  b1, h1p, N);

    // ---- layer 2 ----
    {
        dim3 grid((N + 63) / 64, 64 / 64);
        gemm_kernel<<<grid, 256, 0, stream>>>(h1p, W2, h2, N, 128, 64);
    }
    att_kernel<1, 64><<<(N + 255) / 256, 256, 0, stream>>>(h2, att_s2, att_d2,
                                                           as2, ad2, N);
    agg_kernel<1, 64, false><<<N, 64, 0, stream>>>(h2, as2, ad2, csr, offs,
                                                   deg, b2, (float*)d_out, N);
}

// Round 9
// 463.190 us; speedup vs baseline: 1.7276x; 1.0801x over previous
//
#include <hip/hip_runtime.h>
#include <math.h>

typedef unsigned short ushort_t;
typedef unsigned int uint_t;
typedef __attribute__((ext_vector_type(8))) short short8;
typedef __attribute__((ext_vector_type(4))) float fx4;

__device__ __forceinline__ float bf16_to_f32(ushort_t u) {
    union { uint_t i; float f; } c;
    c.i = ((uint_t)u) << 16;
    return c.f;
}
__device__ __forceinline__ ushort_t f32_to_bf16(float f) {
    union { float f; uint_t i; } c;
    c.f = f;
    const uint_t x = c.i;
    return (ushort_t)((x + 0x7fffu + ((x >> 16) & 1u)) >> 16);
}

// ---- W transpose + bf16 convert: WT[m][k] = bf16(W[k][m]) ----------------
__global__ void convT_kernel(const float* __restrict__ W,
                             ushort_t* __restrict__ WT, int k, int m) {
    const int idx = blockIdx.x * 256 + threadIdx.x;
    if (idx >= k * m) return;
    const int mm = idx / k;
    const int kk = idx % k;
    WT[idx] = f32_to_bf16(W[(size_t)kk * m + mm]);
}

// ---- MFMA GEMM: C[n][TILES*16](bf16) = A[n][k] * B[k][TILES*16] ----------
// BT[col][k] bf16 (pre-transposed). 4 waves/block; wave w -> rows
// blk*64 + w*16 + (lane&15), all TILES col-tiles. No LDS.
// Fragment maps (gfx950, verified): A: m=lane&15, k=quad*8+j;
// B: n=lane&15, k=quad*8+j; C/D: col=lane&15, row=quad*4+reg.
template <int TILES, bool A_F32>
__global__ __launch_bounds__(256) void mfma_gemm_kernel(
    const void* __restrict__ Avoid, const ushort_t* __restrict__ BT,
    ushort_t* __restrict__ C, int n, int k) {
    const int tid = threadIdx.x;
    const int wave = tid >> 6;
    const int lane = tid & 63;
    const int l15 = lane & 15;
    const int quad = lane >> 4;
    const int m = TILES * 16;
    const int row = blockIdx.x * 64 + wave * 16 + l15;
    const int rowc = min(row, n - 1);
    fx4 acc[TILES];
#pragma unroll
    for (int t = 0; t < TILES; ++t) acc[t] = (fx4){0.f, 0.f, 0.f, 0.f};

    const int nchunk = k >> 5;
    for (int kc = 0; kc < nchunk; ++kc) {
        const int kbase = kc * 32 + quad * 8;
        short8 afrag;
        if (A_F32) {
            const float* A = (const float*)Avoid;
            const fx4* ap = (const fx4*)(A + (size_t)rowc * k + kbase);
            const fx4 x0 = ap[0];
            const fx4 x1 = ap[1];
            union { short8 v; ushort_t u[8]; } af;
            af.u[0] = f32_to_bf16(x0[0]);
            af.u[1] = f32_to_bf16(x0[1]);
            af.u[2] = f32_to_bf16(x0[2]);
            af.u[3] = f32_to_bf16(x0[3]);
            af.u[4] = f32_to_bf16(x1[0]);
            af.u[5] = f32_to_bf16(x1[1]);
            af.u[6] = f32_to_bf16(x1[2]);
            af.u[7] = f32_to_bf16(x1[3]);
            afrag = af.v;
        } else {
            const ushort_t* A = (const ushort_t*)Avoid;
            afrag = *(const short8*)(A + (size_t)rowc * k + kbase);
        }
#pragma unroll
        for (int t = 0; t < TILES; ++t) {
            const short8 bfrag =
                *(const short8*)(BT + (size_t)(t * 16 + l15) * k + kbase);
            acc[t] = __builtin_amdgcn_mfma_f32_16x16x32_bf16(afrag, bfrag,
                                                             acc[t], 0, 0, 0);
        }
    }
    const int crow0 = blockIdx.x * 64 + wave * 16 + quad * 4;
#pragma unroll
    for (int t = 0; t < TILES; ++t) {
#pragma unroll
        for (int r = 0; r < 4; ++r) {
            const int rr = crow0 + r;
            if (rr < n) C[(size_t)rr * m + t * 16 + l15] = f32_to_bf16(acc[t][r]);
        }
    }
}

// ------------- per-node attention coefficients a_src, a_dst ---------------
template <int H, int C>
__global__ void att_kernel(const ushort_t* __restrict__ h,
                           const float* __restrict__ att_s,
                           const float* __restrict__ att_d,
                           float* __restrict__ as_, float* __restrict__ ad_,
                           int n) {
    const int idx = blockIdx.x * blockDim.x + threadIdx.x;
    if (idx >= n * H) return;
    const int node = idx / H;
    const int hh = idx % H;
    const ushort_t* hp = h + (size_t)node * H * C + hh * C;
    float s0 = 0.f, s1 = 0.f;
#pragma unroll
    for (int c = 0; c < C; ++c) {
        const float v = bf16_to_f32(hp[c]);
        s0 += v * att_s[hh * C + c];
        s1 += v * att_d[hh * C + c];
    }
    as_[idx] = s0;
    ad_[idx] = s1;
}

// ------------------- CSR build via binned counting sort -------------------
__global__ __launch_bounds__(1024) void hist_kernel(const int* __restrict__ dst,
                                                    int* __restrict__ histG,
                                                    int e, int chunk, int NB,
                                                    int G) {
    __shared__ int hl[512];
    for (int b = threadIdx.x; b < NB; b += 1024) hl[b] = 0;
    __syncthreads();
    const int g = blockIdx.x;
    const int lo = g * chunk;
    const int hi = min(lo + chunk, e);
    for (int i = lo + threadIdx.x; i < hi; i += 1024)
        atomicAdd(&hl[dst[i] >> 8], 1);
    __syncthreads();
    for (int b = threadIdx.x; b < NB; b += 1024) histG[b * G + g] = hl[b];
}

__global__ __launch_bounds__(1024) void scan1_kernel(const int* __restrict__ in,
                                                     int* __restrict__ out,
                                                     int* __restrict__ sums,
                                                     int n) {
    __shared__ int s[1024];
    const int t = threadIdx.x;
    const int i = blockIdx.x * 1024 + t;
    const int v = (i < n) ? in[i] : 0;
    s[t] = v;
    __syncthreads();
    for (int d = 1; d < 1024; d <<= 1) {
        const int x = (t >= d) ? s[t - d] : 0;
        __syncthreads();
        s[t] += x;
        __syncthreads();
    }
    if (i < n) out[i] = s[t] - v;
    if (t == 1023) sums[blockIdx.x] = s[1023];
}

__global__ __launch_bounds__(128) void scan2_kernel(int* sums, int nb) {
    __shared__ int s[128];
    const int t = threadIdx.x;
    const int v = (t < nb) ? sums[t] : 0;
    s[t] = v;
    __syncthreads();
    for (int d = 1; d < 128; d <<= 1) {
        const int x = (t >= d) ? s[t - d] : 0;
        __syncthreads();
        s[t] += x;
        __syncthreads();
    }
    if (t < nb) sums[t] = s[t] - v;
}

__global__ __launch_bounds__(1024) void scan3_kernel(int* __restrict__ out,
                                                     const int* __restrict__ sums,
                                                     int n) {
    const int i = blockIdx.x * 1024 + threadIdx.x;
    if (i < n) out[i] += sums[blockIdx.x];
}

__global__ __launch_bounds__(1024) void bin_kernel(const int* __restrict__ src,
                                                   const int* __restrict__ dst,
                                                   const int* __restrict__ base,
                                                   int2* __restrict__ binned,
                                                   int e, int chunk, int NB,
                                                   int G) {
    __shared__ int cur[512];
    const int g = blockIdx.x;
    for (int b = threadIdx.x; b < NB; b += 1024) cur[b] = base[b * G + g];
    __syncthreads();
    const int lo = g * chunk;
    const int hi = min(lo + chunk, e);
    for (int i = lo + threadIdx.x; i < hi; i += 1024) {
        const int d = dst[i];
        const int p = atomicAdd(&cur[d >> 8], 1);
        binned[p] = make_int2(src[i], d);
    }
}

#define BUILD_CAP 6144
__global__ __launch_bounds__(256) void build_kernel(
    const int2* __restrict__ binned, const int* __restrict__ base,
    int* __restrict__ csr, int* __restrict__ deg, int* __restrict__ offs,
    int e, int n, int NB, int G) {
    __shared__ int2 ep[BUILD_CAP];
    __shared__ int degL[256];
    __shared__ int offL[256];
    __shared__ int curL[256];
    const int b = blockIdx.x;
    const int tid = threadIdx.x;
    const int start = base[b * G];
    const int end = (b == NB - 1) ? e : base[(b + 1) * G];
    const int cnt = end - start;
    const bool stage = (cnt <= BUILD_CAP);
    degL[tid] = 0;
    if (stage)
        for (int i = tid; i < cnt; i += 256) ep[i] = binned[start + i];
    __syncthreads();
    if (stage) {
        for (int i = tid; i < cnt; i += 256) atomicAdd(&degL[ep[i].y & 255], 1);
    } else {
        for (int i = tid; i < cnt; i += 256)
            atomicAdd(&degL[binned[start + i].y & 255], 1);
    }
    __syncthreads();
    const int v = degL[tid];
    offL[tid] = v;
    __syncthreads();
    for (int d = 1; d < 256; d <<= 1) {
        const int x = (tid >= d) ? offL[tid - d] : 0;
        __syncthreads();
        offL[tid] += x;
        __syncthreads();
    }
    const int excl = offL[tid] - v;
    curL[tid] = excl;
    const int node = (b << 8) + tid;
    if (node < n) {
        deg[node] = v;
        offs[node] = start + excl;
    }
    __syncthreads();
    if (stage) {
        for (int i = tid; i < cnt; i += 256) {
            const int p = atomicAdd(&curL[ep[i].y & 255], 1);
            csr[start + p] = ep[i].x;
        }
    } else {
        for (int i = tid; i < cnt; i += 256) {
            const int2 pr = binned[start + i];
            const int p = atomicAdd(&curL[pr.y & 255], 1);
            csr[start + p] = pr.x;
        }
    }
}

// --------- single-pass gather-aggregate + fused softmax denominator -------
template <int H, int C, bool DO_ELU, bool OUT_BF16>
__global__ __launch_bounds__(64) void agg_kernel(
    const ushort_t* __restrict__ h, const float* __restrict__ a_src,
    const float* __restrict__ a_dst, const int* __restrict__ csr,
    const int* __restrict__ offs, const int* __restrict__ deg,
    const float* __restrict__ bias, void* __restrict__ outv, int n) {
    constexpr int HC = H * C;
    constexpr int R = HC / 64;  // 2 (layer1) or 1 (layer2)
    constexpr int U = 8;        // edge chunk size
    const int dst = blockIdx.x;
    const int lane = threadIdx.x;
    const int start = offs[dst];
    const int d = deg[dst];
    const int myh = lane & (H - 1);
    const int ch0 = lane * R;
    const int hh = ch0 / C;
    const float advm = a_dst[dst * H + myh];
    float acc0 = 0.f, acc1 = 0.f;
    float L = 0.f;

    {
        float e = a_src[dst * H + myh] + advm;
        e = fmaxf(e, 0.2f * e);
        const float p = __expf(e);
        L += p;
        const float a = (H > 1) ? __shfl(p, hh) : p;
        const ushort_t* hp = h + (size_t)dst * HC + ch0;
        if (R == 2) {
            const uint_t v = *(const uint_t*)hp;
            acc0 += a * bf16_to_f32((ushort_t)(v & 0xffffu));
            acc1 += a * bf16_to_f32((ushort_t)(v >> 16));
        } else {
            acc0 += a * bf16_to_f32(hp[0]);
        }
    }

    int j = 0;
    for (; j + U <= d; j += U) {
        int s[U];
        float es[U];
        uint_t hv[U];
#pragma unroll
        for (int u = 0; u < U; ++u) s[u] = csr[start + j + u];
#pragma unroll
        for (int u = 0; u < U; ++u) es[u] = a_src[s[u] * H + myh];
#pragma unroll
        for (int u = 0; u < U; ++u) {
            const ushort_t* hp = h + (size_t)s[u] * HC + ch0;
            if (R == 2) hv[u] = *(const uint_t*)hp;
            else hv[u] = (uint_t)hp[0];
        }
#pragma unroll
        for (int u = 0; u < U; ++u) {
            float e = es[u] + advm;
            e = fmaxf(e, 0.2f * e);
            const float p = __expf(e);
            L += p;
            const float a = (H > 1) ? __shfl(p, hh) : p;
            if (R == 2) {
                acc0 += a * bf16_to_f32((ushort_t)(hv[u] & 0xffffu));
                acc1 += a * bf16_to_f32((ushort_t)(hv[u] >> 16));
            } else {
                acc0 += a * bf16_to_f32((ushort_t)hv[u]);
            }
        }
    }
    for (; j < d; ++j) {
        const int src = csr[start + j];
        float e = a_src[src * H + myh] + advm;
        e = fmaxf(e, 0.2f * e);
        const float p = __expf(e);
        L += p;
        const float a = (H > 1) ? __shfl(p, hh) : p;
        const ushort_t* hp = h + (size_t)src * HC + ch0;
        if (R == 2) {
            const uint_t v = *(const uint_t*)hp;
            acc0 += a * bf16_to_f32((ushort_t)(v & 0xffffu));
            acc1 += a * bf16_to_f32((ushort_t)(v >> 16));
        } else {
            acc0 += a * bf16_to_f32(hp[0]);
        }
    }

    const float Ld = (H > 1) ? __shfl(L, hh) : L;
    const float linv = 1.f / (Ld + 1e-16f);
    float r0 = acc0 * linv + bias[ch0];
    if (DO_ELU) r0 = (r0 > 0.f) ? r0 : (__expf(r0) - 1.f);
    if (R == 2) {
        float r1 = acc1 * linv + bias[ch0 + 1];
        if (DO_ELU) r1 = (r1 > 0.f) ? r1 : (__expf(r1) - 1.f);
        if (OUT_BF16) {
            const uint_t packed =
                (uint_t)f32_to_bf16(r0) | ((uint_t)f32_to_bf16(r1) << 16);
            *(uint_t*)((ushort_t*)outv + (size_t)dst * HC + ch0) = packed;
        } else {
            *(float2*)((float*)outv + (size_t)dst * HC + ch0) =
                make_float2(r0, r1);
        }
    } else {
        if (OUT_BF16)
            ((ushort_t*)outv)[(size_t)dst * HC + ch0] = f32_to_bf16(r0);
        else
            ((float*)outv)[(size_t)dst * HC + ch0] = r0;
    }
}

// --------------------------------------------------------------------------
extern "C" void kernel_launch(void* const* d_in, const int* in_sizes, int n_in,
                              void* d_out, int out_size, void* d_ws,
                              size_t ws_size, hipStream_t stream) {
    const float* x = (const float*)d_in[0];
    const int* ei = (const int*)d_in[1];
    const float* W1 = (const float*)d_in[2];
    const float* att_s1 = (const float*)d_in[3];
    const float* att_d1 = (const float*)d_in[4];
    const float* b1 = (const float*)d_in[5];
    const float* W2 = (const float*)d_in[6];
    const float* att_s2 = (const float*)d_in[7];
    const float* att_d2 = (const float*)d_in[8];
    const float* b2 = (const float*)d_in[9];

    const int N = in_sizes[0] / 256;  // 100000
    const int E = in_sizes[1] / 2;    // 1600000
    const int* srcp = ei;
    const int* dstp = ei + E;

    const int NB = (N + 255) >> 8;  // 391 buckets of 256 nodes
    const int G = 128;
    const int NBG = NB * G;
    const int chunk = (E + G - 1) / G;
    const int nbs = (NBG + 1023) / 1024;

    // workspace layout
    float* as1 = (float*)d_ws;           // N*4
    float* ad1 = as1 + (size_t)N * 4;    // N*4
    float* as2 = ad1 + (size_t)N * 4;    // N
    float* ad2 = as2 + N;                // N
    int* histG = (int*)(ad2 + N);        // NBG
    int* base = histG + NBG;             // NBG
    int* sums = base + NBG;              // 128
    int* deg = sums + 128;               // N
    int* offs = deg + N;                 // N
    int* csr = offs + N;                 // E
    int2* binned = (int2*)(csr + E);     // E pairs (dead after build)
    ushort_t* h1 = (ushort_t*)binned;    // N*128 bf16 (overlays binned)
    ushort_t* h2 = h1 + (size_t)N * 128; // N*64 bf16
    ushort_t* h1p = h2 + (size_t)N * 64; // N*128 bf16 (agg1 out, gemm2 A)
    ushort_t* W1T = h1p + (size_t)N * 128;  // 128*256
    ushort_t* W2T = W1T + 128 * 256;        // 64*128

    // ---- weight transpose + bf16 convert ----
    convT_kernel<<<(256 * 128 + 255) / 256, 256, 0, stream>>>(W1, W1T, 256, 128);
    convT_kernel<<<(128 * 64 + 255) / 256, 256, 0, stream>>>(W2, W2T, 128, 64);

    // ---- CSR build (binned counting sort, no global atomics) ----
    hist_kernel<<<G, 1024, 0, stream>>>(dstp, histG, E, chunk, NB, G);
    scan1_kernel<<<nbs, 1024, 0, stream>>>(histG, base, sums, NBG);
    scan2_kernel<<<1, 128, 0, stream>>>(sums, nbs);
    scan3_kernel<<<nbs, 1024, 0, stream>>>(base, sums, NBG);
    bin_kernel<<<G, 1024, 0, stream>>>(srcp, dstp, base, binned, E, chunk, NB,
                                       G);
    build_kernel<<<NB, 256, 0, stream>>>(binned, base, csr, deg, offs, E, N,
                                         NB, G);

    const int gblk = (N + 63) / 64;  // 1563

    // ---- layer 1 ----
    mfma_gemm_kernel<8, true><<<gblk, 256, 0, stream>>>(x, W1T, h1, N, 256);
    att_kernel<4, 32><<<(N * 4 + 255) / 256, 256, 0, stream>>>(h1, att_s1,
                                                               att_d1, as1,
                                                               ad1, N);
    agg_kernel<4, 32, true, true><<<N, 64, 0, stream>>>(h1, as1, ad1, csr,
                                                        offs, deg, b1, h1p, N);

    // ---- layer 2 ----
    mfma_gemm_kernel<4, false><<<gblk, 256, 0, stream>>>(h1p, W2T, h2, N, 128);
    att_kernel<1, 64><<<(N + 255) / 256, 256, 0, stream>>>(h2, att_s2, att_d2,
                                                           as2, ad2, N);
    agg_kernel<1, 64, false, false><<<N, 64, 0, stream>>>(h2, as2, ad2, csr,
                                                          offs, deg, b2, d_out,
                                                          N);
}